// Round 4
// baseline (87.925 us; speedup 1.0000x reference)
//
#include <hip/hip_runtime.h>
#include <stdint.h>

// ALCOVE RBF: out[b,e] = exp(-C * sum_d attn[d] * |E[e,d] - X[b,d]|)
// BATCH=2048, NE=2048, ND=128, f32 in/out.
//
// R4: v_sad_u32 measured ~quarter-rate on gfx950 (R2/R3 both plateau at the
// 27 us quarter-rate floor despite 4x different LDS traffic). Revert inner
// loop to full-rate fp32: v_sub_f32 + v_add_f32 with abs() source modifier
// (asm-pinned) = 2 ops/term -> 13.7 us VALU floor.
//
// attn >= 0, so attn_d*|x-e| == |attn_d*x - attn_d*e|: pre-scale by attn
// during staging; inner loop is pure sub + abs-add.
//
// Layout (= R3): block 256 thr (4 waves), tile 32(b) x 256(e), KC=32.
// Wave w owns b-rows 8w..8w+7 -> Xs reads are wave-uniform (LDS broadcast).
// Lane owns e = 4*lane..+3 -> Es read is one conflict-free ds_read_b128.
// Es stride 260 words: reads stay 16B-aligned/conflict-free, staging writes
// 4-way conflicted (negligible). Register prefetch of chunk c+1 overlaps
// compute of chunk c.

#define BATCH 2048
#define NE 2048
#define ND 128
#define CCONST 6.5f

#define TB 32
#define TE 256
#define KC 32
#define SE 260              // Es word-stride per d (256 + 4 pad)
#define NCHUNK (ND / KC)    // 4

// acc += |t|, with |.| as a free VOP3 source modifier (full-rate v_add_f32)
#define AA(acc, x, e)                                                  \
  {                                                                    \
    float t_ = (x) - (e);                                              \
    asm("v_add_f32 %0, %0, abs(%1)" : "+v"(acc) : "v"(t_));            \
  }

__global__ __launch_bounds__(256, 2)
void alcove_rbf_kernel(const float* __restrict__ X,
                       const float* __restrict__ E,
                       const float* __restrict__ A,
                       float* __restrict__ out) {
  __shared__ __align__(16) float Es[KC * SE];  // [d][e] padded, 32.5 KB
  __shared__ __align__(16) float Xs[KC * TB];  // [d][b]          4 KB

  const int tid = threadIdx.x;
  const int lane = tid & 63;
  const int w = tid >> 6;              // wave id 0..3 -> b-rows 8w..8w+7
  const int e0 = blockIdx.x * TE;      // 8 e-tiles
  const int b0 = blockIdx.y * TB;      // 64 b-tiles

  const int c4 = tid & 7;              // float4 column in chunk (0..7)
  const int srow = tid >> 3;           // staging row 0..31

  float acc[8][4];
#pragma unroll
  for (int j = 0; j < 8; ++j)
#pragma unroll
    for (int i = 0; i < 4; ++i) acc[j][i] = 0.f;

  // ---- prefetch chunk 0 into registers ----
  float4 eP[8], xP, aP;
  {
    aP = reinterpret_cast<const float4*>(A)[c4];
#pragma unroll
    for (int it = 0; it < 8; ++it)
      eP[it] = reinterpret_cast<const float4*>(
                   E + (size_t)(e0 + it * 32 + srow) * ND)[c4];
    xP = reinterpret_cast<const float4*>(X + (size_t)(b0 + srow) * ND)[c4];
  }

#pragma unroll 1
  for (int c = 0; c < NCHUNK; ++c) {
    if (c) __syncthreads();            // LDS safe to overwrite

    // ---- stage regs -> LDS, pre-scaled by attn ----
    const int dbase = 4 * c4;
#pragma unroll
    for (int it = 0; it < 8; ++it) {
      int row = it * 32 + srow;
      Es[(dbase + 0) * SE + row] = eP[it].x * aP.x;
      Es[(dbase + 1) * SE + row] = eP[it].y * aP.y;
      Es[(dbase + 2) * SE + row] = eP[it].z * aP.z;
      Es[(dbase + 3) * SE + row] = eP[it].w * aP.w;
    }
    Xs[(dbase + 0) * TB + srow] = xP.x * aP.x;
    Xs[(dbase + 1) * TB + srow] = xP.y * aP.y;
    Xs[(dbase + 2) * TB + srow] = xP.z * aP.z;
    Xs[(dbase + 3) * TB + srow] = xP.w * aP.w;
    __syncthreads();

    // ---- prefetch next chunk (waits sink to next staging) ----
    if (c + 1 < NCHUNK) {
      const int kn = (c + 1) * KC;
      aP = reinterpret_cast<const float4*>(A + kn)[c4];
#pragma unroll
      for (int it = 0; it < 8; ++it)
        eP[it] = reinterpret_cast<const float4*>(
                     E + (size_t)(e0 + it * 32 + srow) * ND + kn)[c4];
      xP = reinterpret_cast<const float4*>(X + (size_t)(b0 + srow) * ND + kn)[c4];
    }

    // ---- compute: 32 sub+abs-add pairs per lane per d ----
    const float4* Es4 = reinterpret_cast<const float4*>(Es);
    const float4* Xs4 = reinterpret_cast<const float4*>(Xs);
#pragma unroll 8
    for (int d = 0; d < KC; ++d) {
      float4 ev = Es4[d * (SE / 4) + lane];        // conflict-free contiguous
      float4 xa = Xs4[d * (TB / 4) + 2 * w];       // wave-uniform broadcast
      float4 xb = Xs4[d * (TB / 4) + 2 * w + 1];
      AA(acc[0][0], xa.x, ev.x); AA(acc[0][1], xa.x, ev.y);
      AA(acc[0][2], xa.x, ev.z); AA(acc[0][3], xa.x, ev.w);
      AA(acc[1][0], xa.y, ev.x); AA(acc[1][1], xa.y, ev.y);
      AA(acc[1][2], xa.y, ev.z); AA(acc[1][3], xa.y, ev.w);
      AA(acc[2][0], xa.z, ev.x); AA(acc[2][1], xa.z, ev.y);
      AA(acc[2][2], xa.z, ev.z); AA(acc[2][3], xa.z, ev.w);
      AA(acc[3][0], xa.w, ev.x); AA(acc[3][1], xa.w, ev.y);
      AA(acc[3][2], xa.w, ev.z); AA(acc[3][3], xa.w, ev.w);
      AA(acc[4][0], xb.x, ev.x); AA(acc[4][1], xb.x, ev.y);
      AA(acc[4][2], xb.x, ev.z); AA(acc[4][3], xb.x, ev.w);
      AA(acc[5][0], xb.y, ev.x); AA(acc[5][1], xb.y, ev.y);
      AA(acc[5][2], xb.y, ev.z); AA(acc[5][3], xb.y, ev.w);
      AA(acc[6][0], xb.z, ev.x); AA(acc[6][1], xb.z, ev.y);
      AA(acc[6][2], xb.z, ev.z); AA(acc[6][3], xb.z, ev.w);
      AA(acc[7][0], xb.w, ev.x); AA(acc[7][1], xb.w, ev.y);
      AA(acc[7][2], xb.w, ev.z); AA(acc[7][3], xb.w, ev.w);
    }
  }

  // ---- epilogue: exp + coalesced float4 stores ----
#pragma unroll
  for (int j = 0; j < 8; ++j) {
    int b = b0 + 8 * w + j;
    float4 o;
    o.x = __expf(-CCONST * acc[j][0]);
    o.y = __expf(-CCONST * acc[j][1]);
    o.z = __expf(-CCONST * acc[j][2]);
    o.w = __expf(-CCONST * acc[j][3]);
    reinterpret_cast<float4*>(out + (size_t)b * NE + e0)[lane] = o;
  }
}

extern "C" void kernel_launch(void* const* d_in, const int* in_sizes, int n_in,
                              void* d_out, int out_size, void* d_ws, size_t ws_size,
                              hipStream_t stream) {
  const float* X = (const float*)d_in[0];   // inputs    (2048,128)
  const float* E = (const float*)d_in[1];   // exemplars (2048,128)
  const float* A = (const float*)d_in[2];   // attn      (128,)
  float* out = (float*)d_out;               // (2048,2048)

  dim3 grid(NE / TE, BATCH / TB);           // (8,64) = 512 blocks = 2/CU
  dim3 block(256);
  alcove_rbf_kernel<<<grid, block, 0, stream>>>(X, E, A, out);
}